// Round 4
// baseline (309.061 us; speedup 1.0000x reference)
//
#include <hip/hip_runtime.h>

typedef unsigned short u16;
typedef __attribute__((ext_vector_type(8))) short bf16x8;
typedef __attribute__((ext_vector_type(4))) float f32x4;

#define DEV static __device__ __forceinline__

DEV u16 f2bf(float f) {
  union { float f; unsigned u; } x; x.f = f;
  return (u16)((x.u + 0x7FFFu + ((x.u >> 16) & 1u)) >> 16);
}
DEV float bf2f(u16 h) { union { unsigned u; float f; } x; x.u = ((unsigned)h) << 16; return x.f; }

DEV void gload16(const void* g, void* l) {
  __builtin_amdgcn_global_load_lds((const __attribute__((address_space(1))) void*)g,
                                   (__attribute__((address_space(3))) void*)l, 16, 0, 0);
}

// ---------------- GroupNorm stats (2-stage) ----------------
__global__ __launch_bounds__(256) void gn_stats_a(const float* __restrict__ x,
                                                  float2* __restrict__ part) {
  const int bg = blockIdx.x >> 5, slice = blockIdx.x & 31;
  const float* base = x + (long)bg * 262144 + slice * 8192;
  float s = 0.f, q = 0.f;
#pragma unroll
  for (int i = 0; i < 8; ++i) {
    float4 v = *(const float4*)(base + i * 1024 + threadIdx.x * 4);
    s += v.x + v.y + v.z + v.w;
    q += v.x * v.x + v.y * v.y + v.z * v.z + v.w * v.w;
  }
#pragma unroll
  for (int o = 32; o; o >>= 1) { s += __shfl_xor(s, o); q += __shfl_xor(q, o); }
  __shared__ float2 red[4];
  if ((threadIdx.x & 63) == 0) red[threadIdx.x >> 6] = make_float2(s, q);
  __syncthreads();
  if (threadIdx.x == 0) {
    float S = 0.f, Q = 0.f;
    for (int i = 0; i < 4; ++i) { S += red[i].x; Q += red[i].y; }
    part[blockIdx.x] = make_float2(S, Q);
  }
}

__global__ void gn_stats_b(const float2* __restrict__ part, float2* __restrict__ stats) {
  float s = 0.f, q = 0.f;
  if (threadIdx.x < 32) {
    float2 p = part[blockIdx.x * 32 + threadIdx.x];
    s = p.x; q = p.y;
  }
#pragma unroll
  for (int o = 32; o; o >>= 1) { s += __shfl_xor(s, o); q += __shfl_xor(q, o); }
  if (threadIdx.x == 0) {
    const float inv = 1.f / 262144.f;
    float mean = s * inv;
    float var = q * inv - mean * mean;
    stats[blockIdx.x] = make_float2(mean, rsqrtf(var + 1e-6f));
  }
}

// Normalize + transpose [b,c,t,p] -> hn[(b*16+t)*1024+p][c] bf16
__global__ __launch_bounds__(256) void gn_apply(const float* __restrict__ x,
                                                const float* __restrict__ gamma,
                                                const float* __restrict__ beta,
                                                const float2* __restrict__ stats,
                                                u16* __restrict__ hn) {
  __shared__ u16 tile[64][65];
  const int p0 = blockIdx.x * 64, c0 = blockIdx.y * 64, bt = blockIdx.z;
  const int b = bt >> 4, t = bt & 15, tid = threadIdx.x;
  const float* xb = x + (long)b * 8388608 + t * 1024;
#pragma unroll 4
  for (int r = 0; r < 16; ++r) {
    int ci = r * 4 + (tid >> 6), pi = tid & 63;
    int c = c0 + ci;
    float2 st = stats[b * 32 + (c >> 4)];
    float v = xb[(long)c * 16384 + p0 + pi];
    v = (v - st.x) * st.y * gamma[c] + beta[c];
    tile[ci][pi] = f2bf(v);
  }
  __syncthreads();
  u16* hb = hn + ((long)bt * 1024 + p0) * 512 + c0;
#pragma unroll 4
  for (int r = 0; r < 16; ++r) {
    int pi = r * 4 + (tid >> 6), ci = tid & 63;
    hb[(long)pi * 512 + ci] = tile[ci][pi];
  }
}

// fp32 -> bf16 weight convert: 4 matrices of 512*512 concatenated (q,k,v, proj)
__global__ __launch_bounds__(256) void wconv(const float* __restrict__ w0, const float* __restrict__ w1,
                                             const float* __restrict__ w2, const float* __restrict__ w3,
                                             u16* __restrict__ dst) {
  int e = (blockIdx.x * 256 + threadIdx.x) * 4;
  const float* src = w0;
  int which = e >> 18, off = e & 262143;
  if (which == 1) src = w1; else if (which == 2) src = w2; else if (which == 3) src = w3;
  float4 v = *(const float4*)(src + off);
  ushort4 o;
  o.x = f2bf(v.x); o.y = f2bf(v.y); o.z = f2bf(v.z); o.w = f2bf(v.w);
  *(ushort4*)(dst + e) = o;
}

__global__ void bcat(const float* __restrict__ qb, const float* __restrict__ kb,
                     const float* __restrict__ vb, float* __restrict__ dst) {
  int i = blockIdx.x * 256 + threadIdx.x;
  if (i < 512) dst[i] = qb[i];
  else if (i < 1024) dst[i] = kb[i - 512];
  else if (i < 1536) dst[i] = vb[i - 1024];
}

// v[bt][p][c] (row stride ldv) -> vT[bt][c][p]  (bf16)
__global__ __launch_bounds__(256) void transpose_pc(const u16* __restrict__ v, int ldv,
                                                    u16* __restrict__ vT) {
  __shared__ u16 tile[64][65];
  const int p0 = blockIdx.x * 64, c0 = blockIdx.y * 64;
  const long bt = blockIdx.z;
  const int tid = threadIdx.x;
  const u16* vb = v + bt * 1024 * (long)ldv;
#pragma unroll 4
  for (int r = 0; r < 16; ++r) {
    int pi = r * 4 + (tid >> 6), ci = tid & 63;
    tile[pi][ci] = vb[(long)(p0 + pi) * ldv + c0 + ci];
  }
  __syncthreads();
  u16* ob = vT + bt * 524288;
#pragma unroll 4
  for (int r = 0; r < 16; ++r) {
    int ci = r * 4 + (tid >> 6), pi = tid & 63;
    ob[(long)(c0 + ci) * 1024 + p0 + pi] = tile[pi][ci];
  }
}

// Row softmax over 1024 bf16 cols, in place. 4 rows/block (1 row per wave).
__global__ __launch_bounds__(256) void softmax_rows_bf16(u16* __restrict__ scores) {
  const int wave = threadIdx.x >> 6, lane = threadIdx.x & 63;
  const long row = (long)blockIdx.x * 4 + wave;
  u16* srow = scores + row * 1024;
  bf16x8 a0 = *(const bf16x8*)(srow + lane * 16);
  bf16x8 a1 = *(const bf16x8*)(srow + lane * 16 + 8);
  float v[16];
#pragma unroll
  for (int j = 0; j < 8; ++j) { v[j] = bf2f((u16)a0[j]); v[8 + j] = bf2f((u16)a1[j]); }
  float m = v[0];
#pragma unroll
  for (int j = 1; j < 16; ++j) m = fmaxf(m, v[j]);
#pragma unroll
  for (int o = 32; o; o >>= 1) m = fmaxf(m, __shfl_xor(m, o));
  const float sc = 0.044194173824159216f;  // 1/sqrt(512)
  float s = 0.f, e[16];
#pragma unroll
  for (int j = 0; j < 16; ++j) { e[j] = __expf((v[j] - m) * sc); s += e[j]; }
#pragma unroll
  for (int o = 32; o; o >>= 1) s += __shfl_xor(s, o);
  const float inv = 1.f / s;
  bf16x8 o0, o1;
#pragma unroll
  for (int j = 0; j < 8; ++j) {
    o0[j] = (short)f2bf(e[j] * inv);
    o1[j] = (short)f2bf(e[8 + j] * inv);
  }
  *(bf16x8*)(srow + lane * 16) = o0;
  *(bf16x8*)(srow + lane * 16 + 8) = o1;
}

// ---------------- NT GEMM, 256x256 tile, BK=64, 8-phase pipeline, deep prefetch ----
// C[m,n] = sum_k A[m,k]*B[n,k] (+bias[n]).  8 waves (2M x 4N), wave tile 128x64.
// 2 LDS buffers x (A 256x64 + B 256x64) bf16 = 128 KB. 4 phases per K-tile.
// Region frees: B halves of cur free after ph2; A halves at tile end; other-buf
// free all tile. Stage schedule (deep): ph0 -> A0(T+1), ph1 -> A1(T+1),
// ph3 -> B0,B1(T+2) (into cur-B, freed at ph2). Boundary: vmcnt(4) keeps
// B01(T+2) in flight (counted, never 0 in steady state); min slack 3 phases,
// B-halves get 5-6 phases (covers HBM-miss latency).
#define SYNC_MID() do { asm volatile("" ::: "memory"); __builtin_amdgcn_s_barrier(); \
  asm volatile("s_waitcnt lgkmcnt(0)" ::: "memory"); __builtin_amdgcn_sched_barrier(0); } while (0)
#define SYNC_END() do { asm volatile("" ::: "memory"); __builtin_amdgcn_s_barrier(); \
  asm volatile("" ::: "memory"); } while (0)

template <bool OUT_BF16, bool HAS_BIAS>
__global__ __launch_bounds__(512, 2) void gemm8p(
    const u16* __restrict__ A, int lda, long sA,
    const u16* __restrict__ B, int ldb, long sB,
    void* __restrict__ Cv, int ldc, long sC,
    const float* __restrict__ bias, int K) {
  __shared__ u16 sm[2 * 32768];  // buf b (bytes): A at b*65536, B at b*65536+32768
  const int tid = threadIdx.x;
  const int wid = tid >> 6, lane = tid & 63;
  const int wm = wid >> 2, wn = wid & 3;

  int bx = blockIdx.x, by = blockIdx.y;
  if (gridDim.z == 1 && (((int)gridDim.x * (int)gridDim.y) & 7) == 0) {
    int gy = gridDim.y;
    int d = by * gridDim.x + bx;            // HW dispatch order (x fastest)
    int per = ((int)gridDim.x * gy) >> 3;
    int w = (d & 7) * per + (d >> 3);       // chunk per XCD
    bx = w / gy; by = w % gy;               // consecutive w share bx (A-panel)
  }
  const long m0 = (long)bx * 256;
  const long n0 = (long)by * 256;
  A += (long)blockIdx.z * sA + m0 * lda;
  B += (long)blockIdx.z * sB + n0 * ldb;
  const int NT = K >> 6;

  f32x4 acc[8][4] = {};

  char* smc = (char*)sm;
  // which: 0=A rows0-127, 1=A rows128-255, 2=B rows0-127, 3=B rows128-255
  auto STAGE_HALF = [&](int kt, int which) {
    const char* src = (const char*)((which < 2) ? A : B);
    const long ldby = 2L * ((which < 2) ? lda : ldb);
    const int rowbase = (which & 1) * 128;
    char* dst = smc + (kt & 1) * 65536 + ((which < 2) ? 0 : 32768) + rowbase * 128;
    const char* gk = src + (long)kt * 128;
#pragma unroll
    for (int i = 0; i < 2; ++i) {
      int rl = i * 64 + (tid >> 3);
      int cb = (tid & 7) * 16;
      int scb = cb ^ ((rl & 7) << 4);
      gload16(gk + (long)(rowbase + rl) * ldby + scb, dst + rl * 128 + cb);
    }
  };

  const int lrow = lane & 15, kslot = (lane >> 4) * 16;
  auto RD_A = [&](int buf, int kk, int mh, bf16x8* af) {
#pragma unroll
    for (int mi = 0; mi < 4; ++mi) {
      int row = wm * 128 + (mh * 4 + mi) * 16 + lrow;
      int cb = (kk * 64 + kslot) ^ ((row & 7) << 4);
      af[mi] = *(const bf16x8*)(smc + buf * 65536 + row * 128 + cb);
    }
  };
  auto RD_B = [&](int buf, int kk, bf16x8* bf) {
#pragma unroll
    for (int ni = 0; ni < 4; ++ni) {
      int row = wn * 64 + ni * 16 + lrow;
      int cb = (kk * 64 + kslot) ^ ((row & 7) << 4);
      bf[ni] = *(const bf16x8*)(smc + buf * 65536 + 32768 + row * 128 + cb);
    }
  };

  // prologue: tile0 all 4 halves + B0,B1(T1); wait leaves B01(T1) in flight
  STAGE_HALF(0, 0); STAGE_HALF(0, 1); STAGE_HALF(0, 2); STAGE_HALF(0, 3);
  if (NT > 1) { STAGE_HALF(1, 2); STAGE_HALF(1, 3); }
  asm volatile("s_waitcnt vmcnt(4)" ::: "memory");
  SYNC_END();

  for (int T = 0; T < NT; ++T) {
    const int cur = T & 1;
    const bool s1 = (T + 1 < NT), s2 = (T + 2 < NT);
    bf16x8 af[4], bf[4];
    // ---- phase 0: kk0, mi 0-3 ----
    RD_B(cur, 0, bf);
    RD_A(cur, 0, 0, af);
    if (s1) STAGE_HALF(T + 1, 0);
    SYNC_MID();
    __builtin_amdgcn_s_setprio(1);
#pragma unroll
    for (int mi = 0; mi < 4; ++mi)
#pragma unroll
      for (int ni = 0; ni < 4; ++ni)
        acc[mi][ni] = __builtin_amdgcn_mfma_f32_16x16x32_bf16(af[mi], bf[ni], acc[mi][ni], 0, 0, 0);
    __builtin_amdgcn_s_setprio(0);
    SYNC_END();
    // ---- phase 1: kk0, mi 4-7 ----
    RD_A(cur, 0, 1, af);
    if (s1) STAGE_HALF(T + 1, 1);
    SYNC_MID();
    __builtin_amdgcn_s_setprio(1);
#pragma unroll
    for (int mi = 0; mi < 4; ++mi)
#pragma unroll
      for (int ni = 0; ni < 4; ++ni)
        acc[4 + mi][ni] = __builtin_amdgcn_mfma_f32_16x16x32_bf16(af[mi], bf[ni], acc[4 + mi][ni], 0, 0, 0);
    __builtin_amdgcn_s_setprio(0);
    SYNC_END();
    // ---- phase 2: kk1, mi 0-3 (no stage; 12 ds_reads) ----
    RD_B(cur, 1, bf);
    RD_A(cur, 1, 0, af);
    SYNC_MID();
    __builtin_amdgcn_s_setprio(1);
#pragma unroll
    for (int mi = 0; mi < 4; ++mi)
#pragma unroll
      for (int ni = 0; ni < 4; ++ni)
        acc[mi][ni] = __builtin_amdgcn_mfma_f32_16x16x32_bf16(af[mi], bf[ni], acc[mi][ni], 0, 0, 0);
    __builtin_amdgcn_s_setprio(0);
    SYNC_END();
    // ---- phase 3: kk1, mi 4-7; stage both B halves of T+2 into cur ----
    RD_A(cur, 1, 1, af);
    if (s2) { STAGE_HALF(T + 2, 2); STAGE_HALF(T + 2, 3); }
    SYNC_MID();
    __builtin_amdgcn_s_setprio(1);
#pragma unroll
    for (int mi = 0; mi < 4; ++mi)
#pragma unroll
      for (int ni = 0; ni < 4; ++ni)
        acc[4 + mi][ni] = __builtin_amdgcn_mfma_f32_16x16x32_bf16(af[mi], bf[ni], acc[4 + mi][ni], 0, 0, 0);
    __builtin_amdgcn_s_setprio(0);
    if (s2) asm volatile("s_waitcnt vmcnt(4)" ::: "memory");
    else    asm volatile("s_waitcnt vmcnt(0)" ::: "memory");
    SYNC_END();
  }

  // C/D layout: col = lane&15, row = (lane>>4)*4 + j
  const int lc = lane & 15, lr = (lane >> 4) * 4;
  if (OUT_BF16) {
    u16* C = (u16*)Cv + (long)blockIdx.z * sC;
#pragma unroll
    for (int mi = 0; mi < 8; ++mi) {
      long r = m0 + wm * 128 + mi * 16 + lr;
#pragma unroll
      for (int ni = 0; ni < 4; ++ni) {
        long c = n0 + wn * 64 + ni * 16 + lc;
        float bv = HAS_BIAS ? bias[c] : 0.f;
#pragma unroll
        for (int j = 0; j < 4; ++j) C[(r + j) * ldc + c] = f2bf(acc[mi][ni][j] + bv);
      }
    }
  } else {
    float* C = (float*)Cv + (long)blockIdx.z * sC;
#pragma unroll
    for (int mi = 0; mi < 8; ++mi) {
      long r = m0 + wm * 128 + mi * 16 + lr;
#pragma unroll
      for (int ni = 0; ni < 4; ++ni) {
        long c = n0 + wn * 64 + ni * 16 + lc;
        float bv = HAS_BIAS ? bias[c] : 0.f;
#pragma unroll
        for (int j = 0; j < 4; ++j) C[(r + j) * ldc + c] = acc[mi][ni][j] + bv;
      }
    }
  }
}

// projout[m][c] (+proj_b) + x -> d_out in [b,c,t,p] layout
__global__ __launch_bounds__(256) void final_write(const float* __restrict__ projout,
                                                   const float* __restrict__ proj_b,
                                                   const float* __restrict__ x,
                                                   float* __restrict__ out) {
  __shared__ float tile[64][65];
  const int p0 = blockIdx.x * 64, c0 = blockIdx.y * 64, bt = blockIdx.z;
  const int b = bt >> 4, t = bt & 15, tid = threadIdx.x;
  const float* pr = projout + ((long)bt * 1024 + p0) * 512 + c0;
#pragma unroll 4
  for (int r = 0; r < 16; ++r) {
    int pi = r * 4 + (tid >> 6), ci = tid & 63;
    tile[pi][ci] = pr[(long)pi * 512 + ci];
  }
  __syncthreads();
  const long obase = (long)b * 8388608 + t * 1024;
#pragma unroll 4
  for (int r = 0; r < 16; ++r) {
    int ci = r * 4 + (tid >> 6), pi = tid & 63;
    long idx = obase + (long)(c0 + ci) * 16384 + p0 + pi;
    out[idx] = x[idx] + proj_b[c0 + ci] + tile[pi][ci];
  }
}

extern "C" void kernel_launch(void* const* d_in, const int* in_sizes, int n_in,
                              void* d_out, int out_size, void* d_ws, size_t ws_size,
                              hipStream_t stream) {
  (void)in_sizes; (void)n_in; (void)out_size;
  const float* x      = (const float*)d_in[0];
  const float* gamma  = (const float*)d_in[1];
  const float* beta   = (const float*)d_in[2];
  const float* q_w    = (const float*)d_in[3];
  const float* q_b    = (const float*)d_in[4];
  const float* k_w    = (const float*)d_in[5];
  const float* k_b    = (const float*)d_in[6];
  const float* v_w    = (const float*)d_in[7];
  const float* v_b    = (const float*)d_in[8];
  const float* proj_w = (const float*)d_in[9];
  const float* proj_b = (const float*)d_in[10];

  // workspace layout (bytes)
  const size_t OFF_WB    = 0;            // 2 MB: wq|wk|wv|wp bf16
  const size_t OFF_BIAS  = 2097152;      // 6 KB: qkv bias
  const size_t OFF_STATS = 2103296;      // 512 B
  const size_t OFF_PART  = 2103808;      // 16 KB
  const size_t OFF_HN    = 2121728;      // 32 MB (reused as vT)
  const size_t OFF_QKV   = 35676160;     // 96 MB: [32768][1536] bf16 (reused as projout fp32)
  const size_t OFF_SC    = 136339456;    // scores bf16: CH frames * 2 MB

  char* ws = (char*)d_ws;
  u16*    wb      = (u16*)(ws + OFF_WB);
  float*  qkvbias = (float*)(ws + OFF_BIAS);
  float2* stats   = (float2*)(ws + OFF_STATS);
  float2* part    = (float2*)(ws + OFF_PART);
  u16*    hn      = (u16*)(ws + OFF_HN);
  u16*    vT      = hn;                       // hn dead after QKV GEMM
  u16*    qkv     = (u16*)(ws + OFF_QKV);
  float*  projout = (float*)(ws + OFF_QKV);   // qkv dead after attention
  u16*    scores  = (u16*)(ws + OFF_SC);

  const int CH = (ws_size >= 237002752ULL) ? 32 : 8;  // frames per attention chunk
  u16* ob = (u16*)(ws + OFF_SC + (size_t)CH * 2097152);

  wconv<<<1024, 256, 0, stream>>>(q_w, k_w, v_w, proj_w, wb);
  bcat<<<6, 256, 0, stream>>>(q_b, k_b, v_b, qkvbias);
  gn_stats_a<<<2048, 256, 0, stream>>>(x, part);
  gn_stats_b<<<64, 64, 0, stream>>>(part, stats);
  gn_apply<<<dim3(16, 8, 32), 256, 0, stream>>>(x, gamma, beta, stats, hn);

  // fused QKV: M=32768, N=1536, K=512 -> qkv bf16 [32768][1536]
  gemm8p<true, true><<<dim3(128, 6, 1), 512, 0, stream>>>(
      hn, 512, 0, wb, 512, 0, qkv, 1536, 0, qkvbias, 512);

  transpose_pc<<<dim3(16, 8, 32), 256, 0, stream>>>(qkv + 1024, 1536, vT);

  for (int ch = 0; ch < 32 / CH; ++ch) {
    long f0 = (long)ch * CH;
    // scores = q @ k^T (bf16 out): M=N=1024, K=512, batched over CH frames
    gemm8p<true, false><<<dim3(4, 4, CH), 512, 0, stream>>>(
        qkv + f0 * 1572864, 1536, 1572864,
        qkv + 512 + f0 * 1572864, 1536, 1572864,
        scores, 1024, 1048576, nullptr, 512);
    softmax_rows_bf16<<<CH * 256, 256, 0, stream>>>(scores);
    // o = P @ vT^T : M=1024, N=512, K=1024
    gemm8p<true, false><<<dim3(4, 2, CH), 512, 0, stream>>>(
        scores, 1024, 1048576,
        vT + f0 * 524288, 1024, 524288,
        ob + f0 * 524288, 512, 524288, nullptr, 1024);
  }

  // proj: M=32768, N=512, K=512 -> fp32
  gemm8p<false, false><<<dim3(128, 2, 1), 512, 0, stream>>>(
      ob, 512, 0, wb + 786432, 512, 0, projout, 512, 0, nullptr, 512);
  final_write<<<dim3(16, 8, 32), 256, 0, stream>>>(projout, proj_b, x, (float*)d_out);
}

// Round 5
// 284.252 us; speedup vs baseline: 1.0873x; 1.0873x over previous
//
#include <hip/hip_runtime.h>

typedef unsigned short u16;
typedef __attribute__((ext_vector_type(8))) short bf16x8;
typedef __attribute__((ext_vector_type(4))) float f32x4;

#define DEV static __device__ __forceinline__

DEV u16 f2bf(float f) {
  union { float f; unsigned u; } x; x.f = f;
  return (u16)((x.u + 0x7FFFu + ((x.u >> 16) & 1u)) >> 16);
}
DEV float bf2f(u16 h) { union { unsigned u; float f; } x; x.u = ((unsigned)h) << 16; return x.f; }

DEV void gload16(const void* g, void* l) {
  __builtin_amdgcn_global_load_lds((const __attribute__((address_space(1))) void*)g,
                                   (__attribute__((address_space(3))) void*)l, 16, 0, 0);
}

// ---------------- GroupNorm stats (2-stage) ----------------
__global__ __launch_bounds__(256) void gn_stats_a(const float* __restrict__ x,
                                                  float2* __restrict__ part) {
  const int bg = blockIdx.x >> 5, slice = blockIdx.x & 31;
  const float* base = x + (long)bg * 262144 + slice * 8192;
  float s = 0.f, q = 0.f;
#pragma unroll
  for (int i = 0; i < 8; ++i) {
    float4 v = *(const float4*)(base + i * 1024 + threadIdx.x * 4);
    s += v.x + v.y + v.z + v.w;
    q += v.x * v.x + v.y * v.y + v.z * v.z + v.w * v.w;
  }
#pragma unroll
  for (int o = 32; o; o >>= 1) { s += __shfl_xor(s, o); q += __shfl_xor(q, o); }
  __shared__ float2 red[4];
  if ((threadIdx.x & 63) == 0) red[threadIdx.x >> 6] = make_float2(s, q);
  __syncthreads();
  if (threadIdx.x == 0) {
    float S = 0.f, Q = 0.f;
    for (int i = 0; i < 4; ++i) { S += red[i].x; Q += red[i].y; }
    part[blockIdx.x] = make_float2(S, Q);
  }
}

__global__ void gn_stats_b(const float2* __restrict__ part, float2* __restrict__ stats) {
  float s = 0.f, q = 0.f;
  if (threadIdx.x < 32) {
    float2 p = part[blockIdx.x * 32 + threadIdx.x];
    s = p.x; q = p.y;
  }
#pragma unroll
  for (int o = 32; o; o >>= 1) { s += __shfl_xor(s, o); q += __shfl_xor(q, o); }
  if (threadIdx.x == 0) {
    const float inv = 1.f / 262144.f;
    float mean = s * inv;
    float var = q * inv - mean * mean;
    stats[blockIdx.x] = make_float2(mean, rsqrtf(var + 1e-6f));
  }
}

// Normalize + transpose [b,c,t,p] -> hn[(b*16+t)*1024+p][c] bf16
__global__ __launch_bounds__(256) void gn_apply(const float* __restrict__ x,
                                                const float* __restrict__ gamma,
                                                const float* __restrict__ beta,
                                                const float2* __restrict__ stats,
                                                u16* __restrict__ hn) {
  __shared__ u16 tile[64][65];
  const int p0 = blockIdx.x * 64, c0 = blockIdx.y * 64, bt = blockIdx.z;
  const int b = bt >> 4, t = bt & 15, tid = threadIdx.x;
  const float* xb = x + (long)b * 8388608 + t * 1024;
#pragma unroll 4
  for (int r = 0; r < 16; ++r) {
    int ci = r * 4 + (tid >> 6), pi = tid & 63;
    int c = c0 + ci;
    float2 st = stats[b * 32 + (c >> 4)];
    float v = xb[(long)c * 16384 + p0 + pi];
    v = (v - st.x) * st.y * gamma[c] + beta[c];
    tile[ci][pi] = f2bf(v);
  }
  __syncthreads();
  u16* hb = hn + ((long)bt * 1024 + p0) * 512 + c0;
#pragma unroll 4
  for (int r = 0; r < 16; ++r) {
    int pi = r * 4 + (tid >> 6), ci = tid & 63;
    hb[(long)pi * 512 + ci] = tile[ci][pi];
  }
}

// fp32 -> bf16 weight convert: 4 matrices of 512*512 concatenated (q,k,v, proj)
__global__ __launch_bounds__(256) void wconv(const float* __restrict__ w0, const float* __restrict__ w1,
                                             const float* __restrict__ w2, const float* __restrict__ w3,
                                             u16* __restrict__ dst) {
  int e = (blockIdx.x * 256 + threadIdx.x) * 4;
  const float* src = w0;
  int which = e >> 18, off = e & 262143;
  if (which == 1) src = w1; else if (which == 2) src = w2; else if (which == 3) src = w3;
  float4 v = *(const float4*)(src + off);
  ushort4 o;
  o.x = f2bf(v.x); o.y = f2bf(v.y); o.z = f2bf(v.z); o.w = f2bf(v.w);
  *(ushort4*)(dst + e) = o;
}

__global__ void bcat(const float* __restrict__ qb, const float* __restrict__ kb,
                     const float* __restrict__ vb, float* __restrict__ dst) {
  int i = blockIdx.x * 256 + threadIdx.x;
  if (i < 512) dst[i] = qb[i];
  else if (i < 1024) dst[i] = kb[i - 512];
  else if (i < 1536) dst[i] = vb[i - 1024];
}

// v[bt][p][c] (row stride ldv) -> vT[bt][c][p]  (bf16)
__global__ __launch_bounds__(256) void transpose_pc(const u16* __restrict__ v, int ldv,
                                                    u16* __restrict__ vT) {
  __shared__ u16 tile[64][65];
  const int p0 = blockIdx.x * 64, c0 = blockIdx.y * 64;
  const long bt = blockIdx.z;
  const int tid = threadIdx.x;
  const u16* vb = v + bt * 1024 * (long)ldv;
#pragma unroll 4
  for (int r = 0; r < 16; ++r) {
    int pi = r * 4 + (tid >> 6), ci = tid & 63;
    tile[pi][ci] = vb[(long)(p0 + pi) * ldv + c0 + ci];
  }
  __syncthreads();
  u16* ob = vT + bt * 524288;
#pragma unroll 4
  for (int r = 0; r < 16; ++r) {
    int ci = r * 4 + (tid >> 6), pi = tid & 63;
    ob[(long)(c0 + ci) * 1024 + p0 + pi] = tile[pi][ci];
  }
}

// Row softmax over 1024 bf16 cols, in place. 4 rows/block (1 row per wave).
__global__ __launch_bounds__(256) void softmax_rows_bf16(u16* __restrict__ scores) {
  const int wave = threadIdx.x >> 6, lane = threadIdx.x & 63;
  const long row = (long)blockIdx.x * 4 + wave;
  u16* srow = scores + row * 1024;
  bf16x8 a0 = *(const bf16x8*)(srow + lane * 16);
  bf16x8 a1 = *(const bf16x8*)(srow + lane * 16 + 8);
  float v[16];
#pragma unroll
  for (int j = 0; j < 8; ++j) { v[j] = bf2f((u16)a0[j]); v[8 + j] = bf2f((u16)a1[j]); }
  float m = v[0];
#pragma unroll
  for (int j = 1; j < 16; ++j) m = fmaxf(m, v[j]);
#pragma unroll
  for (int o = 32; o; o >>= 1) m = fmaxf(m, __shfl_xor(m, o));
  const float sc = 0.044194173824159216f;  // 1/sqrt(512)
  float s = 0.f, e[16];
#pragma unroll
  for (int j = 0; j < 16; ++j) { e[j] = __expf((v[j] - m) * sc); s += e[j]; }
#pragma unroll
  for (int o = 32; o; o >>= 1) s += __shfl_xor(s, o);
  const float inv = 1.f / s;
  bf16x8 o0, o1;
#pragma unroll
  for (int j = 0; j < 8; ++j) {
    o0[j] = (short)f2bf(e[j] * inv);
    o1[j] = (short)f2bf(e[8 + j] * inv);
  }
  *(bf16x8*)(srow + lane * 16) = o0;
  *(bf16x8*)(srow + lane * 16 + 8) = o1;
}

// ---------------- NT GEMM, 256x256 tile, BK=64, 8-phase, hoisted addressing -------
// C[m,n] = sum_k A[m,k]*B[n,k] (+bias[n]).  8 waves (2M x 4N), wave tile 128x64.
// 2 LDS buffers x (A 256x64 + B 256x64) bf16 = 128 KB. 4 phases per K-tile.
// ALL addresses precomputed: LDS reads = 4 regs (a0,a1,b0,b1; mh1=+8192 imm,
// frag=+2048 imm, kk1 = ^64, buf toggle = ^65536); stages = 8 persistent global
// pointers (+128 B/tile) + linear dst base with literal offsets.
// Stage schedule: ph0 A0(T+1), ph1 A1(T+1), ph3 B01(T+2) into cur-B (freed ph2).
// Boundary: vmcnt(4) leaves B01(T+2) in flight (counted, never 0 mid-loop).
#define SYNC_MID() do { asm volatile("" ::: "memory"); __builtin_amdgcn_s_barrier(); \
  asm volatile("s_waitcnt lgkmcnt(0)" ::: "memory"); __builtin_amdgcn_sched_barrier(0); } while (0)
#define SYNC_END() do { asm volatile("" ::: "memory"); __builtin_amdgcn_s_barrier(); \
  asm volatile("" ::: "memory"); } while (0)

template <bool OUT_BF16, bool HAS_BIAS>
__global__ __launch_bounds__(512, 2) void gemm8p(
    const u16* __restrict__ A, int lda, long sA,
    const u16* __restrict__ B, int ldb, long sB,
    void* __restrict__ Cv, int ldc, long sC,
    const float* __restrict__ bias, int K) {
  __shared__ u16 sm[2 * 32768];
  char* smc = (char*)sm;
  const int tid = threadIdx.x;
  const int wid = tid >> 6, lane = tid & 63;
  const int wm = wid >> 2, wn = wid & 3;

  // bijective XCD-chunked swizzle over the full (x,y,z) grid
  int bx = blockIdx.x, by = blockIdx.y, bz = blockIdx.z;
  {
    unsigned gx = gridDim.x, gy = gridDim.y;
    unsigned total = gx * gy * gridDim.z;
    if ((total & 7u) == 0) {
      unsigned gxy = gx * gy;
      unsigned d = (blockIdx.z * gy + blockIdx.y) * gx + blockIdx.x;
      unsigned w = (d & 7u) * (total >> 3) + (d >> 3);
      bz = w / gxy; unsigned r = w - (unsigned)bz * gxy;
      bx = r / gy;  by = r - (unsigned)bx * gy;
    }
  }
  const long m0 = (long)bx * 256, n0 = (long)by * 256;
  const char* Ab = (const char*)(A + (long)bz * sA + m0 * lda);
  const char* Bb = (const char*)(B + (long)bz * sB + n0 * ldb);
  const int NT = K >> 6;
  const long lda2 = 2L * lda, ldb2 = 2L * ldb;

  // staging addresses (src pre-swizzled, dst linear)
  const int r8 = tid >> 3;
  const int sw2 = (r8 & 7) << 4;
  const int cb0 = ((tid & 7) * 16) ^ sw2;
  const int dB = r8 * 128 + (tid & 7) * 16;
  const char* gA00 = Ab + (long)(r8      ) * lda2 + cb0;
  const char* gA01 = Ab + (long)(r8 +  64) * lda2 + cb0;
  const char* gA10 = Ab + (long)(r8 + 128) * lda2 + cb0;
  const char* gA11 = Ab + (long)(r8 + 192) * lda2 + cb0;
  const char* gB00 = Bb + (long)(r8      ) * ldb2 + cb0;
  const char* gB01 = Bb + (long)(r8 +  64) * ldb2 + cb0;
  const char* gB10 = Bb + (long)(r8 + 128) * ldb2 + cb0;
  const char* gB11 = Bb + (long)(r8 + 192) * ldb2 + cb0;

  // LDS read base offsets (buf0); frag +2048, mh1 +8192, kk1 ^64, buf ^65536
  const int lrow = lane & 15, kslot = (lane >> 4) * 16;
  const int sw = (lrow & 7) << 4;
  int a0 = (wm * 128 + lrow) * 128 + (kslot ^ sw);
  int a1 = a0 ^ 64;
  int b0 = 32768 + (wn * 64 + lrow) * 128 + (kslot ^ sw);
  int b1 = b0 ^ 64;

  f32x4 acc[8][4] = {};

#define STG(p, dof, bufbit) gload16((p), smc + ((bufbit) << 16) + (dof))
#define RD4(dst, off) do { \
    dst[0] = *(const bf16x8*)(smc + (off));          \
    dst[1] = *(const bf16x8*)(smc + (off) + 2048);   \
    dst[2] = *(const bf16x8*)(smc + (off) + 4096);   \
    dst[3] = *(const bf16x8*)(smc + (off) + 6144);   \
  } while (0)
#define MFMA16(ah, bh, accb) do { \
    __builtin_amdgcn_s_setprio(1); \
    _Pragma("unroll") \
    for (int mi = 0; mi < 4; ++mi) \
      _Pragma("unroll") \
      for (int ni = 0; ni < 4; ++ni) \
        acc[(accb) + mi][ni] = __builtin_amdgcn_mfma_f32_16x16x32_bf16(ah[mi], bh[ni], acc[(accb) + mi][ni], 0, 0, 0); \
    __builtin_amdgcn_s_setprio(0); \
  } while (0)

  // prologue: tile0 A+B -> buf0; tile1 B -> buf1; leave tile1-B in flight
  STG(gA00, dB, 0);         STG(gA01, dB + 8192, 0);
  STG(gA10, dB + 16384, 0); STG(gA11, dB + 24576, 0);
  STG(gB00, dB + 32768, 0); STG(gB01, dB + 40960, 0);
  STG(gB10, dB + 49152, 0); STG(gB11, dB + 57344, 0);
  STG(gB00 + 128, dB + 32768, 1); STG(gB01 + 128, dB + 40960, 1);
  STG(gB10 + 128, dB + 49152, 1); STG(gB11 + 128, dB + 57344, 1);
  gA00 += 128; gA01 += 128; gA10 += 128; gA11 += 128;   // -> tile1
  gB00 += 256; gB01 += 256; gB10 += 256; gB11 += 256;   // -> tile2
  asm volatile("s_waitcnt vmcnt(4)" ::: "memory");
  SYNC_END();

  for (int T = 0; T < NT; ++T) {
    const int cur = T & 1, nxt = cur ^ 1;
    const bool s1 = (T + 1 < NT), s2 = (T + 2 < NT);
    bf16x8 af[4], bf[4];
    // ---- ph0: mh0 kk0, stage A-half0(T+1) ----
    RD4(bf, b0);
    RD4(af, a0);
    if (s1) { STG(gA00, dB, nxt); STG(gA01, dB + 8192, nxt); }
    SYNC_MID();
    MFMA16(af, bf, 0);
    SYNC_END();
    // ---- ph1: mh1 kk0, stage A-half1(T+1) ----
    RD4(af, a0 + 8192);
    if (s1) { STG(gA10, dB + 16384, nxt); STG(gA11, dB + 24576, nxt); }
    SYNC_MID();
    MFMA16(af, bf, 4);
    SYNC_END();
    // ---- ph2: mh0 kk1 ----
    RD4(bf, b1);
    RD4(af, a1);
    SYNC_MID();
    MFMA16(af, bf, 0);
    SYNC_END();
    // ---- ph3: mh1 kk1, stage B01(T+2) into cur-B ----
    RD4(af, a1 + 8192);
    if (s2) { STG(gB00, dB + 32768, cur); STG(gB01, dB + 40960, cur);
              STG(gB10, dB + 49152, cur); STG(gB11, dB + 57344, cur); }
    SYNC_MID();
    MFMA16(af, bf, 4);
    if (s2) asm volatile("s_waitcnt vmcnt(4)" ::: "memory");
    else    asm volatile("s_waitcnt vmcnt(0)" ::: "memory");
    SYNC_END();
    // advance
    gA00 += 128; gA01 += 128; gA10 += 128; gA11 += 128;
    gB00 += 128; gB01 += 128; gB10 += 128; gB11 += 128;
    a0 ^= 65536; a1 ^= 65536; b0 ^= 65536; b1 ^= 65536;
  }
#undef STG
#undef RD4
#undef MFMA16

  // C/D layout: col = lane&15, row = (lane>>4)*4 + j
  const int lc = lane & 15, lr = (lane >> 4) * 4;
  if (OUT_BF16) {
    u16* C = (u16*)Cv + (long)bz * sC;
#pragma unroll
    for (int mi = 0; mi < 8; ++mi) {
      long r = m0 + wm * 128 + mi * 16 + lr;
#pragma unroll
      for (int ni = 0; ni < 4; ++ni) {
        long c = n0 + wn * 64 + ni * 16 + lc;
        float bv = HAS_BIAS ? bias[c] : 0.f;
#pragma unroll
        for (int j = 0; j < 4; ++j) C[(r + j) * ldc + c] = f2bf(acc[mi][ni][j] + bv);
      }
    }
  } else {
    float* C = (float*)Cv + (long)bz * sC;
#pragma unroll
    for (int mi = 0; mi < 8; ++mi) {
      long r = m0 + wm * 128 + mi * 16 + lr;
#pragma unroll
      for (int ni = 0; ni < 4; ++ni) {
        long c = n0 + wn * 64 + ni * 16 + lc;
        float bv = HAS_BIAS ? bias[c] : 0.f;
#pragma unroll
        for (int j = 0; j < 4; ++j) C[(r + j) * ldc + c] = acc[mi][ni][j] + bv;
      }
    }
  }
}

// projout[m][c] bf16 (+proj_b) + x -> d_out in [b,c,t,p] layout
__global__ __launch_bounds__(256) void final_write(const u16* __restrict__ projout,
                                                   const float* __restrict__ proj_b,
                                                   const float* __restrict__ x,
                                                   float* __restrict__ out) {
  __shared__ float tile[64][65];
  const int p0 = blockIdx.x * 64, c0 = blockIdx.y * 64, bt = blockIdx.z;
  const int b = bt >> 4, t = bt & 15, tid = threadIdx.x;
  const u16* pr = projout + ((long)bt * 1024 + p0) * 512 + c0;
#pragma unroll 4
  for (int r = 0; r < 16; ++r) {
    int pi = r * 4 + (tid >> 6), ci = tid & 63;
    tile[pi][ci] = bf2f(pr[(long)pi * 512 + ci]);
  }
  __syncthreads();
  const long obase = (long)b * 8388608 + t * 1024;
#pragma unroll 4
  for (int r = 0; r < 16; ++r) {
    int ci = r * 4 + (tid >> 6), pi = tid & 63;
    long idx = obase + (long)(c0 + ci) * 16384 + p0 + pi;
    out[idx] = x[idx] + proj_b[c0 + ci] + tile[pi][ci];
  }
}

extern "C" void kernel_launch(void* const* d_in, const int* in_sizes, int n_in,
                              void* d_out, int out_size, void* d_ws, size_t ws_size,
                              hipStream_t stream) {
  (void)in_sizes; (void)n_in; (void)out_size;
  const float* x      = (const float*)d_in[0];
  const float* gamma  = (const float*)d_in[1];
  const float* beta   = (const float*)d_in[2];
  const float* q_w    = (const float*)d_in[3];
  const float* q_b    = (const float*)d_in[4];
  const float* k_w    = (const float*)d_in[5];
  const float* k_b    = (const float*)d_in[6];
  const float* v_w    = (const float*)d_in[7];
  const float* v_b    = (const float*)d_in[8];
  const float* proj_w = (const float*)d_in[9];
  const float* proj_b = (const float*)d_in[10];

  // workspace layout (bytes)
  const size_t OFF_WB    = 0;            // 2 MB: wq|wk|wv|wp bf16
  const size_t OFF_BIAS  = 2097152;      // 6 KB: qkv bias
  const size_t OFF_STATS = 2103296;      // 512 B
  const size_t OFF_PART  = 2103808;      // 16 KB
  const size_t OFF_HN    = 2121728;      // 32 MB (reused as vT)
  const size_t OFF_QKV   = 35676160;     // 96 MB: [32768][1536] bf16 (later projout bf16)
  const size_t OFF_SC    = 136339456;    // scores bf16: CH frames * 2 MB

  char* ws = (char*)d_ws;
  u16*    wb      = (u16*)(ws + OFF_WB);
  float*  qkvbias = (float*)(ws + OFF_BIAS);
  float2* stats   = (float2*)(ws + OFF_STATS);
  float2* part    = (float2*)(ws + OFF_PART);
  u16*    hn      = (u16*)(ws + OFF_HN);
  u16*    vT      = hn;                       // hn dead after QKV GEMM
  u16*    qkv     = (u16*)(ws + OFF_QKV);
  u16*    projout = (u16*)(ws + OFF_QKV);     // qkv dead after attention
  u16*    scores  = (u16*)(ws + OFF_SC);

  const int CH = (ws_size >= 237002752ULL) ? 32 : 8;  // frames per attention chunk
  u16* ob = (u16*)(ws + OFF_SC + (size_t)CH * 2097152);

  wconv<<<1024, 256, 0, stream>>>(q_w, k_w, v_w, proj_w, wb);
  bcat<<<6, 256, 0, stream>>>(q_b, k_b, v_b, qkvbias);
  gn_stats_a<<<2048, 256, 0, stream>>>(x, part);
  gn_stats_b<<<64, 64, 0, stream>>>(part, stats);
  gn_apply<<<dim3(16, 8, 32), 256, 0, stream>>>(x, gamma, beta, stats, hn);

  // fused QKV: M=32768, N=1536, K=512 -> qkv bf16 [32768][1536]
  gemm8p<true, true><<<dim3(128, 6, 1), 512, 0, stream>>>(
      hn, 512, 0, wb, 512, 0, qkv, 1536, 0, qkvbias, 512);

  transpose_pc<<<dim3(16, 8, 32), 256, 0, stream>>>(qkv + 1024, 1536, vT);

  for (int ch = 0; ch < 32 / CH; ++ch) {
    long f0 = (long)ch * CH;
    // scores = q @ k^T (bf16 out): M=N=1024, K=512, batched over CH frames
    gemm8p<true, false><<<dim3(4, 4, CH), 512, 0, stream>>>(
        qkv + f0 * 1572864, 1536, 1572864,
        qkv + 512 + f0 * 1572864, 1536, 1572864,
        scores, 1024, 1048576, nullptr, 512);
    softmax_rows_bf16<<<CH * 256, 256, 0, stream>>>(scores);
    // o = P @ vT^T : M=1024, N=512, K=1024
    gemm8p<true, false><<<dim3(4, 2, CH), 512, 0, stream>>>(
        scores, 1024, 1048576,
        vT + f0 * 524288, 1024, 524288,
        ob + f0 * 524288, 512, 524288, nullptr, 1024);
  }

  // proj: M=32768, N=512, K=512 -> bf16
  gemm8p<true, false><<<dim3(128, 2, 1), 512, 0, stream>>>(
      ob, 512, 0, wb + 786432, 512, 0, projout, 512, 0, nullptr, 512);
  final_write<<<dim3(16, 8, 32), 256, 0, stream>>>(projout, proj_b, x, (float*)d_out);
}